// Round 15
// baseline (4877.543 us; speedup 1.0000x reference)
//
#include <hip/hip_runtime.h>

#define T_LEN 1024
#define B_SZ  256
#define D_DIM 64
#define E_DIM 512
#define H_DIM 256

#define SA 552   // flow A-tile LDS stride (bf16 elems) — verified 2-way max
#define SH 264   // flow hid-tile LDS stride
#define SF 66    // flow stf stride (floats)
#define ROWB 1152  // esn LDS row stride BYTES (576 fp16)

#define FLOW_LDS (32*SA*2 + 32*SH*2 + 32*4)   // 52,352 B -> 3 blocks/CU
#define ESN_LDS  (96*ROWB)                    // W 64 rows + 2x hA 16 rows = 110,592 B

using short8 = __attribute__((ext_vector_type(8))) short;
using half8  = __attribute__((ext_vector_type(8))) _Float16;
using f32x4  = __attribute__((ext_vector_type(4))) float;
typedef unsigned long long ull;

static __device__ __forceinline__ unsigned short f2bf(float v) {
    unsigned u = __float_as_uint(v);
    u += 0x7FFFu + ((u >> 16) & 1u);   // RNE to bf16
    return (unsigned short)(u >> 16);
}
static __device__ __forceinline__ unsigned short f2h(float v) {
    _Float16 h = (_Float16)v;
    unsigned short u;
    __builtin_memcpy(&u, &h, 2);
    return u;
}
static __device__ __forceinline__ float h2f(unsigned short u) {
    _Float16 h;
    __builtin_memcpy(&h, &u, 2);
    return (float)h;
}
static __device__ __forceinline__ float fast_tanh(float x) {
    x = fminf(15.f, fmaxf(-15.f, x));
    float e = __expf(2.f * x);
    return (e - 1.f) / (e + 1.f);
}
// XOR bank swizzle within each 128B sub-block of a 1152B row (both-sides involution).
static __device__ __forceinline__ int rswz(int row, int byte_in_row) {
    return row * ROWB + (byte_in_row ^ ((row & 7) << 4));
}

// ---- Weight prep (R9 verified) ----
__global__ void prep_kernel(const float* __restrict__ W_in, const float* __restrict__ W_s,
                            const float* __restrict__ W_t, const float* __restrict__ W_res,
                            const float* __restrict__ W_inp, const float* __restrict__ x_seq,
                            unsigned short* __restrict__ W_inF, unsigned short* __restrict__ W_stF,
                            unsigned short* __restrict__ W_packo, unsigned short* __restrict__ x_h) {
    int idx = blockIdx.x * blockDim.x + threadIdx.x;
    int stride = gridDim.x * blockDim.x;
    const int total1 = 8 * 16 * 17 * 64 * 8;        // W_inF
    for (int i = idx; i < total1; i += stride) {
        int j    = i & 7;
        int lane = (i >> 3) & 63;
        int ks   = (i >> 9) % 17;
        int nt   = (i / (512 * 17)) & 15;
        int ls   = i / (512 * 17 * 16);
        int side = ls & 1, l = ls >> 1;
        int n = nt * 16 + (lane & 15);
        int k = ks * 32 + (lane >> 4) * 8 + j;
        int ksrc = (k < 32) ? (side == 0 ? 32 + k : k) : (k + 32);
        W_inF[i] = f2bf(W_in[(l * 576 + ksrc) * H_DIM + n]);
    }
    const int total2 = 8 * 4 * 8 * 64 * 8;          // W_stF
    for (int i = idx; i < total2; i += stride) {
        int j    = i & 7;
        int lane = (i >> 3) & 63;
        int ks   = (i >> 9) & 7;
        int nt   = (i >> 12) & 3;
        int ls   = i >> 14;
        int side = ls & 1, l = ls >> 1;
        int nst = nt * 16 + (lane & 15);
        int k   = ks * 32 + (lane >> 4) * 8 + j;
        int j32 = nst & 31;
        int d   = side ? (32 + j32) : j32;
        float v = (nst < 32) ? W_s[(l * H_DIM + k) * D_DIM + d] : W_t[(l * H_DIM + k) * D_DIM + d];
        W_stF[i] = f2bf(v);
    }
    const int total3 = E_DIM * 576;
    for (int i = idx; i < total3; i += stride) {
        int k = i % 576;
        int n = i / 576;
        float v = (k < E_DIM) ? W_res[n * E_DIM + k] : W_inp[(k - E_DIM) * E_DIM + n];
        W_packo[i] = f2h(v);
    }
    const int total4 = T_LEN * B_SZ * D_DIM;
    for (int i = idx; i < total4; i += stride)
        x_h[i] = f2h(x_seq[i]);
}

// ---- One pipelined ESN phase: chain X computes step t; then polls chain O at
// step tread and issues O's reads (kept in flight via counted vmcnt). ----
static __device__ __forceinline__ void esn_phase(
        char* ha, char* Wlb, int r0x, unsigned int* gcx,
        ull (&hvx)[8], uint2& xvx,
        int r0o, unsigned int* gco, ull (&hvo)[8], uint2& xvo,
        int t, int tl, int tc, int tread, bool do_reads,
        const unsigned short* __restrict__ x_h,
        unsigned short* __restrict__ h_store,
        unsigned short* __restrict__ h_buf,
        int tid, int wave, int lane, int n0) {
    const int arow = lane & 15;
    const int kq   = lane >> 4;
    const int srow = tid >> 4;
    const int seg  = tid & 15;
    const size_t HB = (size_t)B_SZ * E_DIM;

    // stage chain X's step-t data (hvx regs -> swizzled LDS)
    #pragma unroll
    for (int qq = 0; qq < 4; ++qq) {
        const int c = seg + 16 * qq;
        uint4 pk;
        __builtin_memcpy(&pk, &hvx[2 * qq], 16);
        *reinterpret_cast<uint4*>(ha + rswz(srow, 16 * c)) = pk;
    }
    *reinterpret_cast<uint2*>(ha + rswz(srow, 1024 + seg * 8)) = xvx;
    __syncthreads();

    if (tl == 0) {   // h_store[0] = bf16(h(t0)) from regs
        #pragma unroll
        for (int qq = 0; qq < 4; ++qq) {
            const int c = seg + 16 * qq;
            unsigned short o[8];
            #pragma unroll
            for (int j = 0; j < 4; ++j) o[j]     = f2bf(h2f((unsigned short)(hvx[2*qq]   >> (16 * j))));
            #pragma unroll
            for (int j = 0; j < 4; ++j) o[4 + j] = f2bf(h2f((unsigned short)(hvx[2*qq+1] >> (16 * j))));
            uint4 pk;
            __builtin_memcpy(&pk, o, 16);
            *reinterpret_cast<uint4*>(&h_store[(size_t)(r0x + srow) * E_DIM + 8 * c]) = pk;
        }
    }

    // MFMA: wave -> 16 cols, K=576 (R9 body)
    f32x4 accA = (f32x4){0.f, 0.f, 0.f, 0.f};
    f32x4 accB = (f32x4){0.f, 0.f, 0.f, 0.f};
    #pragma unroll
    for (int ks = 0; ks < 18; ++ks) {
        half8 a = *reinterpret_cast<const half8*>(ha + rswz(arow, ks * 64 + kq * 16));
        half8 b = *reinterpret_cast<const half8*>(Wlb + rswz(wave * 16 + arow, ks * 64 + kq * 16));
        if (ks & 1) accB = __builtin_amdgcn_mfma_f32_16x16x32_f16(a, b, accB, 0, 0, 0);
        else        accA = __builtin_amdgcn_mfma_f32_16x16x32_f16(a, b, accA, 0, 0, 0);
    }
    f32x4 acc = accA + accB;

    // stores: h(t+1) slice -> ring (system scope) + h_store bf16
    unsigned short* hb_w = h_buf + (size_t)((t + 1) & 1) * HB;
    const int ncol = n0 + wave * 16 + arow;
    #pragma unroll
    for (int i = 0; i < 4; ++i) {
        const int row = r0x + kq * 4 + i;
        float hvf = fast_tanh(acc[i]);
        __hip_atomic_store(&hb_w[(size_t)row * E_DIM + ncol], f2h(hvf),
                           __ATOMIC_RELAXED, __HIP_MEMORY_SCOPE_SYSTEM);
        if (tl + 1 < tc)
            h_store[((size_t)(tl + 1) * B_SZ + row) * E_DIM + ncol] = f2bf(hvf);
    }

    if (do_reads) {
        // poll chain O at step tread, then issue O's reads (9 loads/thread, LAST-issued)
        if (tid == 0) {
            while (__hip_atomic_fetch_add(gco, 0u, __ATOMIC_RELAXED,
                                          __HIP_MEMORY_SCOPE_AGENT) < 8u * (unsigned)tread)
                __builtin_amdgcn_s_sleep(1);
        }
        __syncthreads();
        asm volatile("" ::: "memory");
        const unsigned short* hb_r = h_buf + (size_t)(tread & 1) * HB;
        const ull* hrow = reinterpret_cast<const ull*>(&hb_r[(size_t)(r0o + srow) * E_DIM]);
        #pragma unroll
        for (int qq = 0; qq < 4; ++qq) {
            const int c = seg + 16 * qq;
            hvo[2*qq]   = __hip_atomic_load(hrow + 2*c,     __ATOMIC_RELAXED, __HIP_MEMORY_SCOPE_SYSTEM);
            hvo[2*qq+1] = __hip_atomic_load(hrow + 2*c + 1, __ATOMIC_RELAXED, __HIP_MEMORY_SCOPE_SYSTEM);
        }
        xvo = *reinterpret_cast<const uint2*>(
            &x_h[((size_t)tread * B_SZ + r0o + srow) * D_DIM + seg * 4]);
        // drain all earlier-issued stores; keep the 9 just-issued reads in flight
        asm volatile("s_waitcnt vmcnt(9)" ::: "memory");
    } else {
        asm volatile("s_waitcnt vmcnt(0)" ::: "memory");
    }
    __syncthreads();
    if (tid == 0)
        __hip_atomic_fetch_add(gcx, 1u, __ATOMIC_RELAXED, __HIP_MEMORY_SCOPE_AGENT);
}

// ---- Phase 1: ESN, two interleaved chains per block (64 blocks x 256 thr). ----
// Block (q = bid&7, m = bid>>3): member m of groups 2q (chain A) and 2q+1 (B).
// W col-slice [64m,64m+64) in swizzled LDS; per iteration A(t) then B(t), each
// phase polling the other chain and prefetching its reads under own compute.
__launch_bounds__(256, 1)
__global__ void esn_kernel(const unsigned short* __restrict__ x_h,
                           const unsigned short* __restrict__ W_pack,
                           unsigned short* __restrict__ h_store /*bf16 [tc][B][E]*/,
                           unsigned short* __restrict__ h_buf   /*fp16 [2][B][E]*/,
                           unsigned int* __restrict__ ctr,
                           int t0, int tc) {
    const int bid  = blockIdx.x;     // 64 blocks
    const int q    = bid & 7;
    const int m    = bid >> 3;
    const int tid  = threadIdx.x;
    const int wave = tid >> 6;
    const int lane = tid & 63;
    const int n0   = m * 64;
    const size_t HB = (size_t)B_SZ * E_DIM;

    const int r0A = (q * 2) * 16;
    const int r0B = (q * 2 + 1) * 16;
    unsigned int* gcA = ctr + (q * 2) * 32;
    unsigned int* gcB = ctr + (q * 2 + 1) * 32;

    extern __shared__ char smem[];
    char* Wlb  = smem;                  // [64][1152B] W-slice, swizzled
    char* hAbA = smem + 64 * ROWB;      // [16][1152B] chain A
    char* hAbB = smem + 80 * ROWB;      // [16][1152B] chain B

    {   // W-slice -> LDS (swizzled write; one-time)
        const int r  = tid & 63;
        const int c0 = (tid >> 6) * 18;
        #pragma unroll
        for (int u = 0; u < 18; ++u) {
            const int byte = 16 * (c0 + u);
            *reinterpret_cast<uint4*>(Wlb + rswz(r, byte)) =
                *reinterpret_cast<const uint4*>(
                    reinterpret_cast<const char*>(&W_pack[(size_t)(n0 + r) * 576]) + byte);
        }
    }

    const int srow = tid >> 4;
    const int seg  = tid & 15;

    ull hvA[8], hvB[8];
    uint2 xvA, xvB;

    // prologue: poll chain A @ t0, load its h + x
    if (tid == 0) {
        while (__hip_atomic_fetch_add(gcA, 0u, __ATOMIC_RELAXED,
                                      __HIP_MEMORY_SCOPE_AGENT) < 8u * (unsigned)t0)
            __builtin_amdgcn_s_sleep(1);
    }
    __syncthreads();
    asm volatile("" ::: "memory");
    {
        const unsigned short* hb_r = h_buf + (size_t)(t0 & 1) * HB;
        const ull* hrow = reinterpret_cast<const ull*>(&hb_r[(size_t)(r0A + srow) * E_DIM]);
        #pragma unroll
        for (int qq = 0; qq < 4; ++qq) {
            const int c = seg + 16 * qq;
            hvA[2*qq]   = __hip_atomic_load(hrow + 2*c,     __ATOMIC_RELAXED, __HIP_MEMORY_SCOPE_SYSTEM);
            hvA[2*qq+1] = __hip_atomic_load(hrow + 2*c + 1, __ATOMIC_RELAXED, __HIP_MEMORY_SCOPE_SYSTEM);
        }
        xvA = *reinterpret_cast<const uint2*>(
            &x_h[((size_t)t0 * B_SZ + r0A + srow) * D_DIM + seg * 4]);
    }

    for (int tl = 0; tl < tc; ++tl) {
        const int t = t0 + tl;
        // phase A: compute A(t); poll B(t), prefetch B's reads
        esn_phase(hAbA, Wlb, r0A, gcA, hvA, xvA,
                  r0B, gcB, hvB, xvB,
                  t, tl, tc, t, true,
                  x_h, h_store, h_buf, tid, wave, lane, n0);
        // phase B: compute B(t); poll A(t+1), prefetch A's reads (skip at last)
        esn_phase(hAbB, Wlb, r0B, gcB, hvB, xvB,
                  r0A, gcA, hvA, xvA,
                  t, tl, tc, t + 1, (tl + 1 < tc),
                  x_h, h_store, h_buf, tid, wave, lane, n0);
    }
}

// ---- Phase 2: flow (R14 verified, byte-identical: 1 subtile/block, 3/CU). ----
__launch_bounds__(256, 3)
__global__ void flow_kernel(const float* __restrict__ x_seq, const unsigned short* __restrict__ h_store,
                            const unsigned short* __restrict__ W_inF, const unsigned short* __restrict__ W_stF,
                            const float* __restrict__ b_in, const float* __restrict__ b_s,
                            const float* __restrict__ b_t, const float* __restrict__ rescale_w,
                            const int* __restrict__ seq_len, float* __restrict__ ll_part,
                            int t0, int tc) {
    const int ttb  = blockIdx.x >> 4;
    const int bt   = blockIdx.x & 15;
    const int tid  = threadIdx.x;
    const int wave = tid >> 6;
    const int lane = tid & 63;

    extern __shared__ char smemf[];
    unsigned short* abf   = reinterpret_cast<unsigned short*>(smemf);   // [32][SA]
    unsigned short* hidbf = abf + 32 * SA;                              // [32][SH]
    float* llacc = reinterpret_cast<float*>(hidbf + 32 * SH);           // [32]
    float* stf   = reinterpret_cast<float*>(hidbf);                     // [32][SF] alias

    const int r8 = tid >> 3;
    const int c8 = tid & 7;

    const int trow = ttb * 2 + (r8 >> 4);
    const int brow = bt * 16 + (r8 & 15);

    float z[8];
    {
        const float* xp = &x_seq[((size_t)(t0 + trow) * B_SZ + brow) * D_DIM + c8 * 8];
        float4 v0 = *reinterpret_cast<const float4*>(xp);
        float4 v1 = *reinterpret_cast<const float4*>(xp + 4);
        z[0] = v0.x; z[1] = v0.y; z[2] = v0.z; z[3] = v0.w;
        z[4] = v1.x; z[5] = v1.y; z[6] = v1.z; z[7] = v1.w;
        const unsigned short* hp = &h_store[((size_t)trow * B_SZ + brow) * E_DIM + c8 * 64];
        unsigned short* ap = &abf[r8 * SA + 32 + c8 * 64];
        #pragma unroll
        for (int q = 0; q < 8; ++q)
            *reinterpret_cast<uint4*>(ap + q * 8) = *reinterpret_cast<const uint4*>(hp + q * 8);
    }
    if (tid < 32) llacc[tid] = 0.f;
    __syncthreads();

    for (int stage = 0; stage < 8; ++stage) {
        const int l = 3 - (stage >> 1);
        const int side = stage & 1;
        const int ls = l * 2 + side;

        {
            const bool act = side ? (c8 < 4) : (c8 >= 4);
            if (act) {
                unsigned short o[8];
                #pragma unroll
                for (int q = 0; q < 8; ++q) o[q] = f2bf(z[q]);
                const int k = side ? (c8 * 8) : ((c8 - 4) * 8);
                uint4 pk;
                __builtin_memcpy(&pk, o, 16);
                *reinterpret_cast<uint4*>(&abf[r8 * SA + k]) = pk;
            }
        }
        __syncthreads();

        const unsigned short* wbase =
            W_inF + ((size_t)(ls * 16 + wave * 4) * 17) * 512 + lane * 8;
        f32x4 acc[2][4];
        #pragma unroll
        for (int mt = 0; mt < 2; ++mt)
            #pragma unroll
            for (int nt = 0; nt < 4; ++nt)
                acc[mt][nt] = (f32x4){0.f, 0.f, 0.f, 0.f};
        const int aoff = (lane & 15) * SA + 8 * (lane >> 4);
        short8 bb[6][4];
        #pragma unroll
        for (int p = 0; p < 6; ++p)
            #pragma unroll
            for (int nt = 0; nt < 4; ++nt)
                bb[p][nt] = *reinterpret_cast<const short8*>(wbase + (size_t)nt * 8704 + p * 512);
        #pragma unroll
        for (int ks = 0; ks < 17; ++ks) {
            const int k0 = ks * 32;
            short8 a0 = *reinterpret_cast<const short8*>(&abf[aoff + k0]);
            short8 a1 = *reinterpret_cast<const short8*>(&abf[16 * SA + aoff + k0]);
            #pragma unroll
            for (int nt = 0; nt < 4; ++nt) {
                acc[0][nt] = __builtin_amdgcn_mfma_f32_16x16x32_bf16(a0, bb[ks % 6][nt], acc[0][nt], 0, 0, 0);
                acc[1][nt] = __builtin_amdgcn_mfma_f32_16x16x32_bf16(a1, bb[ks % 6][nt], acc[1][nt], 0, 0, 0);
            }
            if (ks + 6 < 17) {
                #pragma unroll
                for (int nt = 0; nt < 4; ++nt)
                    bb[ks % 6][nt] = *reinterpret_cast<const short8*>(
                        wbase + (size_t)nt * 8704 + (ks + 6) * 512);
            }
        }
        #pragma unroll
        for (int mt = 0; mt < 2; ++mt)
            #pragma unroll
            for (int nt = 0; nt < 4; ++nt) {
                const int n = wave * 64 + nt * 16 + (lane & 15);
                const float bias = b_in[l * H_DIM + n];
                #pragma unroll
                for (int i = 0; i < 4; ++i) {
                    const int row = mt * 16 + (lane >> 4) * 4 + i;
                    hidbf[row * SH + n] = f2bf(fast_tanh(acc[mt][nt][i] + bias));
                }
            }
        __syncthreads();

        const unsigned short* wstb =
            W_stF + ((size_t)(ls * 4 + wave) * 8) * 512 + lane * 8;
        f32x4 acc2[2];
        acc2[0] = (f32x4){0.f,0.f,0.f,0.f};
        acc2[1] = (f32x4){0.f,0.f,0.f,0.f};
        const int hoff = (lane & 15) * SH + 8 * (lane >> 4);
        const int nst  = wave * 16 + (lane & 15);
        short8 bs0 = *reinterpret_cast<const short8*>(wstb);
        #pragma unroll
        for (int ks = 0; ks < 8; ++ks) {
            short8 bcur = bs0;
            if (ks + 1 < 8) bs0 = *reinterpret_cast<const short8*>(wstb + (ks + 1) * 512);
            const int k0 = ks * 32;
            short8 a0 = *reinterpret_cast<const short8*>(&hidbf[hoff + k0]);
            short8 a1 = *reinterpret_cast<const short8*>(&hidbf[16 * SH + hoff + k0]);
            acc2[0] = __builtin_amdgcn_mfma_f32_16x16x32_bf16(a0, bcur, acc2[0], 0, 0, 0);
            acc2[1] = __builtin_amdgcn_mfma_f32_16x16x32_bf16(a1, bcur, acc2[1], 0, 0, 0);
        }
        __syncthreads();
        {
            const int j = nst & 31;
            const int d = side ? (32 + j) : j;
            const bool is_s = (nst < 32);
            const float bias = is_s ? b_s[l * D_DIM + d] : b_t[l * D_DIM + d];
            const float rs = rescale_w[d];
            #pragma unroll
            for (int mt = 0; mt < 2; ++mt)
                #pragma unroll
                for (int i = 0; i < 4; ++i) {
                    const int row = mt * 16 + (lane >> 4) * 4 + i;
                    const float v = acc2[mt][i] + bias;
                    stf[row * SF + nst] = is_s ? (fast_tanh(v) * rs) : v;
                }
        }
        __syncthreads();
        {
            const bool act = side ? (c8 >= 4) : (c8 < 4);
            if (act) {
                const int jb = (c8 & 3) * 8;
                float p = 0.f;
                #pragma unroll
                for (int q = 0; q < 8; ++q) {
                    const float sv = stf[r8 * SF + jb + q];
                    const float iv = stf[r8 * SF + 32 + jb + q];
                    z[q] = (z[q] - iv) * __expf(-sv);
                    p += sv;
                }
                p += __shfl_xor(p, 1);
                p += __shfl_xor(p, 2);
                if ((c8 & 3) == 0) llacc[r8] -= p;
            }
        }
    } // stage

    __syncthreads();
    {
        float zs = 0.f;
        #pragma unroll
        for (int q = 0; q < 8; ++q) zs += z[q] * z[q];
        zs += __shfl_xor(zs, 1);
        zs += __shfl_xor(zs, 2);
        zs += __shfl_xor(zs, 4);
        if (c8 == 0) {
            float ll = llacc[r8] - 0.5f * zs - 58.812066125f;   // 0.5*64*log(2*pi)
            llacc[r8] = ((t0 + trow) < seq_len[brow]) ? ll : 0.f;
        }
    }
    __syncthreads();
    if (tid < 16)
        ll_part[((size_t)((t0 >> 1) + ttb)) * B_SZ + bt * 16 + tid] =
            llacc[tid] + llacc[16 + tid];
}

__global__ void reduce_kernel(const float* __restrict__ ll_part, float* __restrict__ out) {
    int b = threadIdx.x;
    float s = 0.f;
    #pragma unroll
    for (int tt = 0; tt < T_LEN / 2; ++tt) s += ll_part[tt * B_SZ + b];
    out[b] = s;
}

extern "C" void kernel_launch(void* const* d_in, const int* in_sizes, int n_in,
                              void* d_out, int out_size, void* d_ws, size_t ws_size,
                              hipStream_t stream) {
    const float* x_seq   = (const float*)d_in[0];
    const int*   seqlen  = (const int*)d_in[1];
    const float* W_in    = (const float*)d_in[3];
    const float* b_in    = (const float*)d_in[4];
    const float* W_s     = (const float*)d_in[5];
    const float* b_s     = (const float*)d_in[6];
    const float* W_t     = (const float*)d_in[7];
    const float* b_t     = (const float*)d_in[8];
    const float* rescale = (const float*)d_in[9];
    const float* W_res   = (const float*)d_in[10];
    const float* W_inp   = (const float*)d_in[11];

    char* ws = (char*)d_ws;
    size_t off = 0;
    unsigned short* W_inF  = (unsigned short*)(ws + off); off += (size_t)8 * 16 * 17 * 64 * 8 * 2;
    unsigned short* W_stF  = (unsigned short*)(ws + off); off += (size_t)8 * 4 * 8 * 64 * 8 * 2;
    unsigned short* W_pack = (unsigned short*)(ws + off); off += (size_t)E_DIM * 576 * 2;
    unsigned short* x_h    = (unsigned short*)(ws + off); off += (size_t)T_LEN * B_SZ * D_DIM * 2;
    float* ll_part = (float*)(ws + off); off += (size_t)(T_LEN / 2) * B_SZ * 4;
    unsigned short* h_buf  = (unsigned short*)(ws + off); off += (size_t)2 * B_SZ * E_DIM * 2;
    unsigned int* ctr = (unsigned int*)(ws + off); off += (size_t)16 * 32 * 4;
    unsigned short* h_store = (unsigned short*)(ws + off);

    size_t per_t = (size_t)B_SZ * E_DIM * 2;
    size_t rem = (ws_size > off) ? (ws_size - off) : 0;
    long long tcl = (long long)(rem / per_t);
    int tc = (int)((tcl > T_LEN) ? T_LEN : tcl);
    tc &= ~15;
    if (tc < 16) tc = 16;

    hipMemsetAsync(h_buf, 0, (size_t)2 * B_SZ * E_DIM * 2, stream);
    hipMemsetAsync(ctr, 0, (size_t)16 * 32 * 4, stream);

    prep_kernel<<<2048, 256, 0, stream>>>(W_in, W_s, W_t, W_res, W_inp, x_seq,
                                          W_inF, W_stF, W_pack, x_h);
    for (int t0 = 0; t0 < T_LEN; t0 += tc) {
        int cur = T_LEN - t0; if (cur > tc) cur = tc;
        esn_kernel<<<64, 256, ESN_LDS, stream>>>(x_h, W_pack, h_store, h_buf, ctr, t0, cur);
        flow_kernel<<<(cur / 2) * 16, 256, FLOW_LDS, stream>>>(x_seq, h_store, W_inF, W_stF,
                                                               b_in, b_s, b_t, rescale, seqlen,
                                                               ll_part, t0, cur);
    }
    reduce_kernel<<<1, B_SZ, 0, stream>>>(ll_part, (float*)d_out);
}

// Round 16
// 3515.827 us; speedup vs baseline: 1.3873x; 1.3873x over previous
//
#include <hip/hip_runtime.h>

#define T_LEN 1024
#define B_SZ  256
#define D_DIM 64
#define E_DIM 512
#define H_DIM 256

#define SA 552   // flow A-tile LDS stride (bf16 elems) — verified 2-way max
#define SH 264   // flow hid-tile LDS stride
#define SF 66    // flow stf stride (floats)
#define ROWB 1152  // esn LDS row stride BYTES (576 fp16)

#define FLOW_LDS (32*SA*2 + 32*SH*2 + 32*4)   // 52,352 B -> 3 blocks/CU

using short8 = __attribute__((ext_vector_type(8))) short;
using half8  = __attribute__((ext_vector_type(8))) _Float16;
using f32x4  = __attribute__((ext_vector_type(4))) float;
typedef unsigned long long ull;

static __device__ __forceinline__ unsigned short f2bf(float v) {
    unsigned u = __float_as_uint(v);
    u += 0x7FFFu + ((u >> 16) & 1u);   // RNE to bf16
    return (unsigned short)(u >> 16);
}
static __device__ __forceinline__ unsigned short f2h(float v) {
    _Float16 h = (_Float16)v;
    unsigned short u;
    __builtin_memcpy(&u, &h, 2);
    return u;
}
static __device__ __forceinline__ float h2f(unsigned short u) {
    _Float16 h;
    __builtin_memcpy(&h, &u, 2);
    return (float)h;
}
static __device__ __forceinline__ float fast_tanh(float x) {
    x = fminf(15.f, fmaxf(-15.f, x));
    float e = __expf(2.f * x);
    return (e - 1.f) / (e + 1.f);
}
// XOR bank swizzle within each 128B sub-block of a 1152B row (both-sides involution).
static __device__ __forceinline__ int rswz(int row, int byte_in_row) {
    return row * ROWB + (byte_in_row ^ ((row & 7) << 4));
}

// ---- Weight prep (R9 verified) ----
__global__ void prep_kernel(const float* __restrict__ W_in, const float* __restrict__ W_s,
                            const float* __restrict__ W_t, const float* __restrict__ W_res,
                            const float* __restrict__ W_inp, const float* __restrict__ x_seq,
                            unsigned short* __restrict__ W_inF, unsigned short* __restrict__ W_stF,
                            unsigned short* __restrict__ W_packo, unsigned short* __restrict__ x_h) {
    int idx = blockIdx.x * blockDim.x + threadIdx.x;
    int stride = gridDim.x * blockDim.x;
    const int total1 = 8 * 16 * 17 * 64 * 8;        // W_inF
    for (int i = idx; i < total1; i += stride) {
        int j    = i & 7;
        int lane = (i >> 3) & 63;
        int ks   = (i >> 9) % 17;
        int nt   = (i / (512 * 17)) & 15;
        int ls   = i / (512 * 17 * 16);
        int side = ls & 1, l = ls >> 1;
        int n = nt * 16 + (lane & 15);
        int k = ks * 32 + (lane >> 4) * 8 + j;
        int ksrc = (k < 32) ? (side == 0 ? 32 + k : k) : (k + 32);
        W_inF[i] = f2bf(W_in[(l * 576 + ksrc) * H_DIM + n]);
    }
    const int total2 = 8 * 4 * 8 * 64 * 8;          // W_stF
    for (int i = idx; i < total2; i += stride) {
        int j    = i & 7;
        int lane = (i >> 3) & 63;
        int ks   = (i >> 9) & 7;
        int nt   = (i >> 12) & 3;
        int ls   = i >> 14;
        int side = ls & 1, l = ls >> 1;
        int nst = nt * 16 + (lane & 15);
        int k   = ks * 32 + (lane >> 4) * 8 + j;
        int j32 = nst & 31;
        int d   = side ? (32 + j32) : j32;
        float v = (nst < 32) ? W_s[(l * H_DIM + k) * D_DIM + d] : W_t[(l * H_DIM + k) * D_DIM + d];
        W_stF[i] = f2bf(v);
    }
    const int total3 = E_DIM * 576;
    for (int i = idx; i < total3; i += stride) {
        int k = i % 576;
        int n = i / 576;
        float v = (k < E_DIM) ? W_res[n * E_DIM + k] : W_inp[(k - E_DIM) * E_DIM + n];
        W_packo[i] = f2h(v);
    }
    const int total4 = T_LEN * B_SZ * D_DIM;
    for (int i = idx; i < total4; i += stride)
        x_h[i] = f2h(x_seq[i]);
}

// ---- Phase 1: ESN (R8/R9 verified protocol; epilogue store-split: ring stores
// drain via counted vmcnt(4) before the flag, h_store HBM writes fly under the
// next step). ----
__launch_bounds__(256, 1)
__global__ void esn_kernel(const unsigned short* __restrict__ x_h,
                           const unsigned short* __restrict__ W_pack,
                           unsigned short* __restrict__ h_store /*bf16 [tc][B][E]*/,
                           unsigned short* __restrict__ h_buf   /*fp16 [2][B][E]*/,
                           unsigned int* __restrict__ ctr,
                           int t0, int tc) {
    const int bid  = blockIdx.x;
    const int g    = bid & 15;
    const int m    = bid >> 4;
    const int tid  = threadIdx.x;
    const int wave = tid >> 6;
    const int lane = tid & 63;
    const int arow = lane & 15;
    const int kq   = lane >> 4;
    const int r0   = g * 16;
    const int n0   = m * 64;
    const size_t HB = (size_t)B_SZ * E_DIM;
    unsigned int* gctr = ctr + g * 32;

    extern __shared__ char smem[];
    char* Wlb = smem;                 // [64][1152B] W-slice, swizzled
    char* hAb = smem + 64 * ROWB;     // [16][1152B] = [h(1024B) | x(128B)], swizzled

    {   // W-slice -> LDS (swizzled write; one-time)
        const int r  = tid & 63;
        const int c0 = (tid >> 6) * 18;
        #pragma unroll
        for (int u = 0; u < 18; ++u) {
            const int byte = 16 * (c0 + u);
            *reinterpret_cast<uint4*>(Wlb + rswz(r, byte)) =
                *reinterpret_cast<const uint4*>(
                    reinterpret_cast<const char*>(&W_pack[(size_t)(n0 + r) * 576]) + byte);
        }
    }

    const int srow = tid >> 4;
    const int seg  = tid & 15;
    const int xrow = tid >> 2, xc = tid & 3;

    for (int tl = 0; tl < tc; ++tl) {
        const int t = t0 + tl;
        const unsigned short* hb_r = h_buf + (size_t)(t & 1) * HB;
        unsigned short*       hb_w = h_buf + (size_t)((t & 1) ^ 1) * HB;

        uint4 xa = {0,0,0,0}, xb = {0,0,0,0};
        if (tid < 64) {
            const unsigned short* xp = &x_h[((size_t)t * B_SZ + r0 + xrow) * D_DIM + xc * 16];
            xa = *reinterpret_cast<const uint4*>(xp);
            xb = *reinterpret_cast<const uint4*>(xp + 8);
        }

        if (tid == 0) {
            while (__hip_atomic_fetch_add(gctr, 0u, __ATOMIC_RELAXED,
                                          __HIP_MEMORY_SCOPE_AGENT) < 8u * (unsigned)t)
                __builtin_amdgcn_s_sleep(1);
        }
        __syncthreads();
        asm volatile("" ::: "memory");

        ull hv[8];
        const ull* hrow = reinterpret_cast<const ull*>(&hb_r[(size_t)(r0 + srow) * E_DIM]);
        #pragma unroll
        for (int q = 0; q < 4; ++q) {
            const int c = seg + 16 * q;
            hv[2*q]   = __hip_atomic_load(hrow + 2*c,     __ATOMIC_RELAXED, __HIP_MEMORY_SCOPE_SYSTEM);
            hv[2*q+1] = __hip_atomic_load(hrow + 2*c + 1, __ATOMIC_RELAXED, __HIP_MEMORY_SCOPE_SYSTEM);
        }
        #pragma unroll
        for (int q = 0; q < 4; ++q) {
            const int c = seg + 16 * q;
            uint4 pk;
            __builtin_memcpy(&pk, &hv[2*q], 16);
            *reinterpret_cast<uint4*>(hAb + rswz(srow, 16 * c)) = pk;
        }
        if (tid < 64) {
            *reinterpret_cast<uint4*>(hAb + rswz(xrow, 1024 + 32 * xc))      = xa;
            *reinterpret_cast<uint4*>(hAb + rswz(xrow, 1024 + 32 * xc + 16)) = xb;
        }
        __syncthreads();

        if (tl == 0) {
            #pragma unroll
            for (int q = 0; q < 4; ++q) {
                const int c = seg + 16 * q;
                unsigned short o[8];
                #pragma unroll
                for (int j = 0; j < 4; ++j) o[j]     = f2bf(h2f((unsigned short)(hv[2*q]   >> (16 * j))));
                #pragma unroll
                for (int j = 0; j < 4; ++j) o[4 + j] = f2bf(h2f((unsigned short)(hv[2*q+1] >> (16 * j))));
                uint4 pk;
                __builtin_memcpy(&pk, o, 16);
                *reinterpret_cast<uint4*>(&h_store[(size_t)(r0 + srow) * E_DIM + 8 * c]) = pk;
            }
        }

        f32x4 accA = (f32x4){0.f, 0.f, 0.f, 0.f};
        f32x4 accB = (f32x4){0.f, 0.f, 0.f, 0.f};
        #pragma unroll
        for (int ks = 0; ks < 18; ++ks) {
            half8 a = *reinterpret_cast<const half8*>(hAb + rswz(arow, ks * 64 + kq * 16));
            half8 b = *reinterpret_cast<const half8*>(Wlb + rswz(wave * 16 + arow, ks * 64 + kq * 16));
            if (ks & 1) accB = __builtin_amdgcn_mfma_f32_16x16x32_f16(a, b, accB, 0, 0, 0);
            else        accA = __builtin_amdgcn_mfma_f32_16x16x32_f16(a, b, accA, 0, 0, 0);
        }
        f32x4 acc = accA + accB;

        // epilogue: ring stores FIRST (protocol), then h_store writes (free-flying)
        const int ncol = n0 + wave * 16 + arow;
        float hvf[4];
        #pragma unroll
        for (int i = 0; i < 4; ++i) hvf[i] = fast_tanh(acc[i]);
        #pragma unroll
        for (int i = 0; i < 4; ++i) {
            const int row = r0 + kq * 4 + i;
            __hip_atomic_store(&hb_w[(size_t)row * E_DIM + ncol], f2h(hvf[i]),
                               __ATOMIC_RELAXED, __HIP_MEMORY_SCOPE_SYSTEM);
        }
        asm volatile("" ::: "memory");   // pin issue order: ring stores before h_store
        if (tl + 1 < tc) {
            #pragma unroll
            for (int i = 0; i < 4; ++i) {
                const int row = r0 + kq * 4 + i;
                h_store[((size_t)(tl + 1) * B_SZ + row) * E_DIM + ncol] = f2bf(hvf[i]);
            }
            // drain the 4 oldest outstanding VMEM stores (= the ring stores);
            // the 4 h_store writes stay in flight under the next step.
            asm volatile("s_waitcnt vmcnt(4)" ::: "memory");
        } else {
            asm volatile("s_waitcnt vmcnt(0)" ::: "memory");
        }
        __syncthreads();
        if (tid == 0)
            __hip_atomic_fetch_add(gctr, 1u, __ATOMIC_RELAXED, __HIP_MEMORY_SCOPE_AGENT);
    }
}

// ---- Phase 2: flow (R14 verified, byte-identical: 1 subtile/block, 3/CU). ----
__launch_bounds__(256, 3)
__global__ void flow_kernel(const float* __restrict__ x_seq, const unsigned short* __restrict__ h_store,
                            const unsigned short* __restrict__ W_inF, const unsigned short* __restrict__ W_stF,
                            const float* __restrict__ b_in, const float* __restrict__ b_s,
                            const float* __restrict__ b_t, const float* __restrict__ rescale_w,
                            const int* __restrict__ seq_len, float* __restrict__ ll_part,
                            int t0, int tc) {
    const int ttb  = blockIdx.x >> 4;    // t-pair index (2 t-rows per block)
    const int bt   = blockIdx.x & 15;
    const int tid  = threadIdx.x;
    const int wave = tid >> 6;
    const int lane = tid & 63;

    extern __shared__ char smemf[];
    unsigned short* abf   = reinterpret_cast<unsigned short*>(smemf);   // [32][SA]
    unsigned short* hidbf = abf + 32 * SA;                              // [32][SH]
    float* llacc = reinterpret_cast<float*>(hidbf + 32 * SH);           // [32]
    float* stf   = reinterpret_cast<float*>(hidbf);                     // [32][SF] alias

    const int r8 = tid >> 3;    // row 0..31
    const int c8 = tid & 7;     // owns dims c8*8 .. c8*8+7

    const int trow = ttb * 2 + (r8 >> 4);
    const int brow = bt * 16 + (r8 & 15);

    float z[8];
    {   // one-time staging: x -> z regs, h -> abf h-part
        const float* xp = &x_seq[((size_t)(t0 + trow) * B_SZ + brow) * D_DIM + c8 * 8];
        float4 v0 = *reinterpret_cast<const float4*>(xp);
        float4 v1 = *reinterpret_cast<const float4*>(xp + 4);
        z[0] = v0.x; z[1] = v0.y; z[2] = v0.z; z[3] = v0.w;
        z[4] = v1.x; z[5] = v1.y; z[6] = v1.z; z[7] = v1.w;
        const unsigned short* hp = &h_store[((size_t)trow * B_SZ + brow) * E_DIM + c8 * 64];
        unsigned short* ap = &abf[r8 * SA + 32 + c8 * 64];
        #pragma unroll
        for (int q = 0; q < 8; ++q)
            *reinterpret_cast<uint4*>(ap + q * 8) = *reinterpret_cast<const uint4*>(hp + q * 8);
    }
    if (tid < 32) llacc[tid] = 0.f;
    __syncthreads();

    for (int stage = 0; stage < 8; ++stage) {
        const int l = 3 - (stage >> 1);
        const int side = stage & 1;
        const int ls = l * 2 + side;

        {   // abf z-build: active half writes its 8 kept-dim cols (thread-local z)
            const bool act = side ? (c8 < 4) : (c8 >= 4);
            if (act) {
                unsigned short o[8];
                #pragma unroll
                for (int q = 0; q < 8; ++q) o[q] = f2bf(z[q]);
                const int k = side ? (c8 * 8) : ((c8 - 4) * 8);
                uint4 pk;
                __builtin_memcpy(&pk, o, 16);
                *reinterpret_cast<uint4*>(&abf[r8 * SA + k]) = pk;
            }
        }
        __syncthreads();

        // hid GEMM: M=32 K=544 N=256 (R9 body)
        const unsigned short* wbase =
            W_inF + ((size_t)(ls * 16 + wave * 4) * 17) * 512 + lane * 8;
        f32x4 acc[2][4];
        #pragma unroll
        for (int mt = 0; mt < 2; ++mt)
            #pragma unroll
            for (int nt = 0; nt < 4; ++nt)
                acc[mt][nt] = (f32x4){0.f, 0.f, 0.f, 0.f};
        const int aoff = (lane & 15) * SA + 8 * (lane >> 4);
        short8 bb[6][4];
        #pragma unroll
        for (int p = 0; p < 6; ++p)
            #pragma unroll
            for (int nt = 0; nt < 4; ++nt)
                bb[p][nt] = *reinterpret_cast<const short8*>(wbase + (size_t)nt * 8704 + p * 512);
        #pragma unroll
        for (int ks = 0; ks < 17; ++ks) {
            const int k0 = ks * 32;
            short8 a0 = *reinterpret_cast<const short8*>(&abf[aoff + k0]);
            short8 a1 = *reinterpret_cast<const short8*>(&abf[16 * SA + aoff + k0]);
            #pragma unroll
            for (int nt = 0; nt < 4; ++nt) {
                acc[0][nt] = __builtin_amdgcn_mfma_f32_16x16x32_bf16(a0, bb[ks % 6][nt], acc[0][nt], 0, 0, 0);
                acc[1][nt] = __builtin_amdgcn_mfma_f32_16x16x32_bf16(a1, bb[ks % 6][nt], acc[1][nt], 0, 0, 0);
            }
            if (ks + 6 < 17) {
                #pragma unroll
                for (int nt = 0; nt < 4; ++nt)
                    bb[ks % 6][nt] = *reinterpret_cast<const short8*>(
                        wbase + (size_t)nt * 8704 + (ks + 6) * 512);
            }
        }
        #pragma unroll
        for (int mt = 0; mt < 2; ++mt)
            #pragma unroll
            for (int nt = 0; nt < 4; ++nt) {
                const int n = wave * 64 + nt * 16 + (lane & 15);
                const float bias = b_in[l * H_DIM + n];
                #pragma unroll
                for (int i = 0; i < 4; ++i) {
                    const int row = mt * 16 + (lane >> 4) * 4 + i;
                    hidbf[row * SH + n] = f2bf(fast_tanh(acc[mt][nt][i] + bias));
                }
            }
        __syncthreads();

        // slope|intercept GEMM: M=32 K=256 N=64 (R9 body)
        const unsigned short* wstb =
            W_stF + ((size_t)(ls * 4 + wave) * 8) * 512 + lane * 8;
        f32x4 acc2[2];
        acc2[0] = (f32x4){0.f,0.f,0.f,0.f};
        acc2[1] = (f32x4){0.f,0.f,0.f,0.f};
        const int hoff = (lane & 15) * SH + 8 * (lane >> 4);
        const int nst  = wave * 16 + (lane & 15);
        short8 bs0 = *reinterpret_cast<const short8*>(wstb);
        #pragma unroll
        for (int ks = 0; ks < 8; ++ks) {
            short8 bcur = bs0;
            if (ks + 1 < 8) bs0 = *reinterpret_cast<const short8*>(wstb + (ks + 1) * 512);
            const int k0 = ks * 32;
            short8 a0 = *reinterpret_cast<const short8*>(&hidbf[hoff + k0]);
            short8 a1 = *reinterpret_cast<const short8*>(&hidbf[16 * SH + hoff + k0]);
            acc2[0] = __builtin_amdgcn_mfma_f32_16x16x32_bf16(a0, bcur, acc2[0], 0, 0, 0);
            acc2[1] = __builtin_amdgcn_mfma_f32_16x16x32_bf16(a1, bcur, acc2[1], 0, 0, 0);
        }
        __syncthreads();   // hidbf reads done before stf (alias) writes
        {
            const int j = nst & 31;
            const int d = side ? (32 + j) : j;
            const bool is_s = (nst < 32);
            const float bias = is_s ? b_s[l * D_DIM + d] : b_t[l * D_DIM + d];
            const float rs = rescale_w[d];
            #pragma unroll
            for (int mt = 0; mt < 2; ++mt)
                #pragma unroll
                for (int i = 0; i < 4; ++i) {
                    const int row = mt * 16 + (lane >> 4) * 4 + i;
                    const float v = acc2[mt][i] + bias;
                    stf[row * SF + nst] = is_s ? (fast_tanh(v) * rs) : v;
                }
        }
        __syncthreads();
        {   // z-update + log-det: active half (owners of updated dims), thread-local z
            const bool act = side ? (c8 >= 4) : (c8 < 4);
            if (act) {
                const int jb = (c8 & 3) * 8;
                float p = 0.f;
                #pragma unroll
                for (int q = 0; q < 8; ++q) {
                    const float sv = stf[r8 * SF + jb + q];
                    const float iv = stf[r8 * SF + 32 + jb + q];
                    z[q] = (z[q] - iv) * __expf(-sv);
                    p += sv;
                }
                p += __shfl_xor(p, 1);
                p += __shfl_xor(p, 2);
                if ((c8 & 3) == 0) llacc[r8] -= p;
            }
        }
        // next iter's post-build sync precedes any hidbf/stf overwrite (R13-verified)
    } // stage

    __syncthreads();
    {   // finalize: zsum + mask per frame
        float zs = 0.f;
        #pragma unroll
        for (int q = 0; q < 8; ++q) zs += z[q] * z[q];
        zs += __shfl_xor(zs, 1);
        zs += __shfl_xor(zs, 2);
        zs += __shfl_xor(zs, 4);
        if (c8 == 0) {
            float ll = llacc[r8] - 0.5f * zs - 58.812066125f;   // 0.5*64*log(2*pi)
            llacc[r8] = ((t0 + trow) < seq_len[brow]) ? ll : 0.f;
        }
    }
    __syncthreads();
    if (tid < 16)
        ll_part[((size_t)((t0 >> 1) + ttb)) * B_SZ + bt * 16 + tid] =
            llacc[tid] + llacc[16 + tid];
}

__global__ void reduce_kernel(const float* __restrict__ ll_part, float* __restrict__ out) {
    int b = threadIdx.x;
    float s = 0.f;
    #pragma unroll
    for (int tt = 0; tt < T_LEN / 2; ++tt) s += ll_part[tt * B_SZ + b];
    out[b] = s;
}

extern "C" void kernel_launch(void* const* d_in, const int* in_sizes, int n_in,
                              void* d_out, int out_size, void* d_ws, size_t ws_size,
                              hipStream_t stream) {
    const float* x_seq   = (const float*)d_in[0];
    const int*   seqlen  = (const int*)d_in[1];
    const float* W_in    = (const float*)d_in[3];
    const float* b_in    = (const float*)d_in[4];
    const float* W_s     = (const float*)d_in[5];
    const float* b_s     = (const float*)d_in[6];
    const float* W_t     = (const float*)d_in[7];
    const float* b_t     = (const float*)d_in[8];
    const float* rescale = (const float*)d_in[9];
    const float* W_res   = (const float*)d_in[10];
    const float* W_inp   = (const float*)d_in[11];

    char* ws = (char*)d_ws;
    size_t off = 0;
    unsigned short* W_inF  = (unsigned short*)(ws + off); off += (size_t)8 * 16 * 17 * 64 * 8 * 2;
    unsigned short* W_stF  = (unsigned short*)(ws + off); off += (size_t)8 * 4 * 8 * 64 * 8 * 2;
    unsigned short* W_pack = (unsigned short*)(ws + off); off += (size_t)E_DIM * 576 * 2;
    unsigned short* x_h    = (unsigned short*)(ws + off); off += (size_t)T_LEN * B_SZ * D_DIM * 2;
    float* ll_part = (float*)(ws + off); off += (size_t)(T_LEN / 2) * B_SZ * 4;
    unsigned short* h_buf  = (unsigned short*)(ws + off); off += (size_t)2 * B_SZ * E_DIM * 2;
    unsigned int* ctr = (unsigned int*)(ws + off); off += (size_t)16 * 32 * 4;
    unsigned short* h_store = (unsigned short*)(ws + off);

    size_t per_t = (size_t)B_SZ * E_DIM * 2;
    size_t rem = (ws_size > off) ? (ws_size - off) : 0;
    long long tcl = (long long)(rem / per_t);
    int tc = (int)((tcl > T_LEN) ? T_LEN : tcl);
    tc &= ~15;
    if (tc < 16) tc = 16;

    hipMemsetAsync(h_buf, 0, (size_t)2 * B_SZ * E_DIM * 2, stream);
    hipMemsetAsync(ctr, 0, (size_t)16 * 32 * 4, stream);

    prep_kernel<<<2048, 256, 0, stream>>>(W_in, W_s, W_t, W_res, W_inp, x_seq,
                                          W_inF, W_stF, W_pack, x_h);
    const int esn_lds = (64 + 16) * ROWB;   // 92,160 B
    for (int t0 = 0; t0 < T_LEN; t0 += tc) {
        int cur = T_LEN - t0; if (cur > tc) cur = tc;
        esn_kernel<<<128, 256, esn_lds, stream>>>(x_h, W_pack, h_store, h_buf, ctr, t0, cur);
        flow_kernel<<<(cur / 2) * 16, 256, FLOW_LDS, stream>>>(x_seq, h_store, W_inF, W_stF,
                                                               b_in, b_s, b_t, rescale, seqlen,
                                                               ll_part, t0, cur);
    }
    reduce_kernel<<<1, B_SZ, 0, stream>>>(ll_part, (float*)d_out);
}